// Round 11
// baseline (485.325 us; speedup 1.0000x reference)
//
#include <hip/hip_runtime.h>
#include <math.h>

#define BATCH 32
#define HH 1024
#define WW 1024
#define WR 513
#define NPIX (HH * WR)
#define TWO_PI_F 6.28318530717958647692f

// Same-wave LDS fence: wait for this wave's own LDS ops.
#define LGKM_SYNC() __asm__ __volatile__("s_waitcnt lgkmcnt(0)" ::: "memory")

__device__ __forceinline__ float2 cadd(float2 a, float2 b) { return make_float2(a.x + b.x, a.y + b.y); }
__device__ __forceinline__ float2 csub(float2 a, float2 b) { return make_float2(a.x - b.x, a.y - b.y); }
__device__ __forceinline__ float2 cmul(float2 a, float2 b) {
    return make_float2(a.x * b.x - a.y * b.y, a.x * b.y + a.y * b.x);
}

// atan2 via odd minimax poly on [0,1] (max err ~1e-5 rad) + quadrant fixup.
__device__ __forceinline__ float fast_atan2f(float y, float x) {
    float ax = __builtin_fabsf(x), ay = __builtin_fabsf(y);
    float mx = fmaxf(ax, ay), mn = fminf(ax, ay);
    float a = mn * __builtin_amdgcn_rcpf(mx);
    float s = a * a;
    float r = fmaf(fmaf(fmaf(fmaf(0.0208351f, s, -0.085133f), s, 0.180141f),
                        s, -0.3302995f), s, 0.999866f) * a;
    if (ay > ax) r = 1.5707963268f - r;
    if (x < 0.0f) r = 3.1415926536f - r;
    return (y < 0.0f) ? -r : r;
}

// ---------------- 16-point building blocks (row_fft path, unchanged) -------
__device__ __forceinline__ constexpr int ridx(int k) { return ((k & 3) << 2) | (k >> 2); }

__device__ __forceinline__ void fft16_ip(float2* d) {
    const float2 Wt1[4] = {{1.f, 0.f},
                           {0.92387953f, -0.38268343f},
                           {0.70710678f, -0.70710678f},
                           {0.38268343f, -0.92387953f}};
    const float2 Wt2[4] = {{1.f, 0.f},
                           {0.70710678f, -0.70710678f},
                           {0.f, -1.f},
                           {-0.70710678f, -0.70710678f}};
    const float2 Wt3[4] = {{1.f, 0.f},
                           {0.38268343f, -0.92387953f},
                           {-0.70710678f, -0.70710678f},
                           {-0.92387953f, 0.38268343f}};
#pragma unroll
    for (int t = 0; t < 4; ++t) {
        float2 x0 = d[t], x1 = d[t + 4], x2 = d[t + 8], x3 = d[t + 12];
        float2 a0 = cadd(x0, x2), a1 = csub(x0, x2), a2 = cadd(x1, x3), a3 = csub(x1, x3);
        d[t]      = cadd(a0, a2);
        d[t + 4]  = cmul(make_float2(a1.x + a3.y, a1.y - a3.x), Wt1[t]);
        d[t + 8]  = cmul(csub(a0, a2), Wt2[t]);
        d[t + 12] = cmul(make_float2(a1.x - a3.y, a1.y + a3.x), Wt3[t]);
    }
#pragma unroll
    for (int r = 0; r < 4; ++r) {
        float2 x0 = d[4 * r], x1 = d[4 * r + 1], x2 = d[4 * r + 2], x3 = d[4 * r + 3];
        float2 e0 = cadd(x0, x2), e1 = csub(x0, x2), e2 = cadd(x1, x3), e3 = csub(x1, x3);
        d[4 * r]     = cadd(e0, e2);
        d[4 * r + 1] = make_float2(e1.x + e3.y, e1.y - e3.x);
        d[4 * r + 2] = csub(e0, e2);
        d[4 * r + 3] = make_float2(e1.x - e3.y, e1.y + e3.x);
    }
}

__device__ __forceinline__ void twiddle_tree(float2 T, float2* Wt) {
    Wt[1] = T;
    Wt[2] = cmul(T, T);
    Wt[3] = cmul(Wt[2], T);
    Wt[4] = cmul(Wt[2], Wt[2]);
    Wt[5] = cmul(Wt[4], Wt[1]);
    Wt[6] = cmul(Wt[4], Wt[2]);
    Wt[7] = cmul(Wt[4], Wt[3]);
    Wt[8] = cmul(Wt[4], Wt[4]);
    Wt[9]  = cmul(Wt[8], Wt[1]);
    Wt[10] = cmul(Wt[8], Wt[2]);
    Wt[11] = cmul(Wt[8], Wt[3]);
    Wt[12] = cmul(Wt[8], Wt[4]);
    Wt[13] = cmul(Wt[8], Wt[5]);
    Wt[14] = cmul(Wt[8], Wt[6]);
    Wt[15] = cmul(Wt[8], Wt[7]);
}

// Wave-level 1024-pt FFT (row_fft_kernel only).
__device__ __forceinline__ void wave_fft1024(float2* v, float2* sb, int lane) {
    fft16_ip(v);
    float s, c;
    __sincosf(-TWO_PI_F * (float)lane * (1.0f / 1024.0f), &s, &c);
    float2 Wt[16];
    twiddle_tree(make_float2(c, s), Wt);
#pragma unroll
    for (int k2 = 1; k2 < 16; ++k2) v[ridx(k2)] = cmul(v[ridx(k2)], Wt[k2]);
    const int k2p = lane & 15, qp = lane >> 4;
#pragma unroll
    for (int k2 = 0; k2 < 16; ++k2) sb[(k2 << 6) | (lane ^ k2)] = v[ridx(k2)];
    LGKM_SYNC();
#pragma unroll
    for (int m = 0; m < 16; ++m) v[m] = sb[(k2p << 6) | ((4 * m + qp) ^ k2p)];
    LGKM_SYNC();
    fft16_ip(v);
    __sincosf(-TWO_PI_F * (float)qp * (1.0f / 64.0f), &s, &c);
    twiddle_tree(make_float2(c, s), Wt);
#pragma unroll
    for (int km = 1; km < 16; ++km) v[ridx(km)] = cmul(v[ridx(km)], Wt[km]);
    const bool hi2 = (lane & 32) != 0, hi1 = (lane & 16) != 0;
#pragma unroll
    for (int m = 0; m < 16; ++m) {
        float2 a = v[m];
        float2 o = make_float2(__shfl_xor(a.x, 32, 64), __shfl_xor(a.y, 32, 64));
        float2 s1 = hi2 ? csub(o, a) : cadd(a, o);
        if (hi2 && hi1) s1 = make_float2(s1.y, -s1.x);
        float2 o2 = make_float2(__shfl_xor(s1.x, 16, 64), __shfl_xor(s1.y, 16, 64));
        v[m] = hi1 ? csub(o2, s1) : cadd(s1, o2);
    }
}

// ---------------------------------------------------------------------------
// Kernel A: unchanged.
// ---------------------------------------------------------------------------
__global__ __launch_bounds__(256, 4) void row_fft_kernel(const float* __restrict__ x,
                                                         float2* __restrict__ rf2) {
    __shared__ float2 buf[4][1024];
    const int t = threadIdx.x, w = t >> 6, lane = t & 63;
    const int b = blockIdx.x >> 7;
    const int h0 = (blockIdx.x & 127) * 8;
    const float* r0 = x + ((long long)b * HH + h0 + 2 * w) * (long long)WW;
    const float* r1 = r0 + WW;
    float2 v[16];
#pragma unroll
    for (int j = 0; j < 16; ++j) v[j] = make_float2(r0[lane + 64 * j], r1[lane + 64 * j]);
    float2* mybuf = &buf[w][0];
    wave_fft1024(v, mybuf, lane);
    const int kq = 2 * ((lane >> 4) & 1) + ((lane >> 5) & 1);
    const int kbase = (lane & 15) + 256 * kq;
#pragma unroll
    for (int m = 0; m < 16; ++m) mybuf[kbase + 16 * m] = v[ridx(m)];
    __syncthreads();
    for (int idx = t; idx < 513 * 8; idx += 256) {
        int k = idx >> 3, j = idx & 7, p = j >> 1, which = j & 1;
        float2 zk = buf[p][k];
        float2 zn = buf[p][(1024 - k) & 1023];
        float2 val = which ? make_float2(0.5f * (zk.y + zn.y), 0.5f * (zn.x - zk.x))
                           : make_float2(0.5f * (zk.x + zn.x), 0.5f * (zk.y - zn.y));
        rf2[((long long)b * WR + k) * 1024 + h0 + j] = val;
    }
}

// ------------------------- 32-point FFT (four-step) ------------------------
__device__ __forceinline__ constexpr int brev5(int k) {
    return ((k & 1) << 4) | ((k & 2) << 2) | (k & 4) | ((k & 8) >> 2) | ((k & 16) >> 4);
}

__device__ __forceinline__ void fft32_dif(float2* d) {
    const float2 TW[16] = {
        {1.f, 0.f},
        {0.98078528f, -0.19509032f},
        {0.92387953f, -0.38268343f},
        {0.83146961f, -0.55557023f},
        {0.70710678f, -0.70710678f},
        {0.55557023f, -0.83146961f},
        {0.38268343f, -0.92387953f},
        {0.19509032f, -0.98078528f},
        {0.f, -1.f},
        {-0.19509032f, -0.98078528f},
        {-0.38268343f, -0.92387953f},
        {-0.55557023f, -0.83146961f},
        {-0.70710678f, -0.70710678f},
        {-0.83146961f, -0.55557023f},
        {-0.92387953f, -0.38268343f},
        {-0.98078528f, -0.19509032f}};
#pragma unroll
    for (int s = 0; s < 5; ++s) {
        const int h = 16 >> s;
#pragma unroll
        for (int b = 0; b < 32; b += 2 * h) {
#pragma unroll
            for (int j = 0; j < h; ++j) {
                float2 a = d[b + j], c = d[b + j + h];
                d[b + j]     = cadd(a, c);
                d[b + j + h] = cmul(csub(a, c), TW[j << s]);
            }
        }
    }
}

// Cartesian Zernike accumulation for one pixel. Identity:
//   rho^p cos(a*theta) = r2^((p-a)/2) * Re((x+iy)^a)   [(p-a) always even]
// so moment(p,a) = sum v * vq_{(p-a)/2} * {Re,Im}(u^a). Removes sqrtf +
// rsqrtf (quarter-rate transcendentals) and both depth-8 Chebyshev chains;
// complex-power tree has depth 4. Exact algebra, bounded domain (rho<=1).
#define ZPIX(VV, YVV)                                                          \
    {                                                                          \
        const float yv_ = (YVV);                                               \
        const float r2_ = xv2 + yv_ * yv_;                                     \
        if (r2_ <= 1.0f) {                                                     \
            cnt += 1.0f;                                                       \
            const float p2_ = r2_ * r2_, p3_ = p2_ * r2_, p4_ = p2_ * p2_;     \
            const float vq0 = (VV);                                            \
            const float vq1 = vq0 * r2_, vq2 = vq0 * p2_,                      \
                        vq3 = vq0 * p3_, vq4 = vq0 * p4_;                      \
            const float cr1 = xv,            ci1 = yv_;                        \
            const float cr2 = xv * xv - yv_ * yv_, ci2 = 2.f * xv * yv_;       \
            const float cr3 = cr2 * cr1 - ci2 * ci1,                           \
                        ci3 = cr2 * ci1 + ci2 * cr1;                           \
            const float cr4 = cr2 * cr2 - ci2 * ci2, ci4 = 2.f * cr2 * ci2;    \
            const float cr5 = cr4 * cr1 - ci4 * ci1,                           \
                        ci5 = cr4 * ci1 + ci4 * cr1;                           \
            const float cr6 = cr4 * cr2 - ci4 * ci2,                           \
                        ci6 = cr4 * ci2 + ci4 * cr2;                           \
            const float cr7 = cr4 * cr3 - ci4 * ci3,                           \
                        ci7 = cr4 * ci3 + ci4 * cr3;                           \
            const float cr8 = cr4 * cr4 - ci4 * ci4, ci8 = 2.f * cr4 * ci4;    \
            const float cr9 = cr8 * cr1 - ci8 * ci1,                           \
                        ci9 = cr8 * ci1 + ci8 * cr1;                           \
            a00 += vq0;                                                        \
            a11 += vq0 * cr1;                                                  \
            a20 += vq1;       a22 += vq0 * cr2;                                \
            a31 += vq1 * cr1; a33 += vq0 * cr3;                                \
            a40 += vq2;       a42 += vq1 * cr2; a44 += vq0 * cr4;              \
            a51 += vq2 * cr1; a53 += vq1 * cr3; a55 += vq0 * cr5;              \
            a60 += vq3;       a62 += vq2 * cr2; a64 += vq1 * cr4;              \
            a66 += vq0 * cr6;                                                  \
            a71 += vq3 * cr1; a73 += vq2 * cr3; a75 += vq1 * cr5;              \
            a77 += vq0 * cr7;                                                  \
            a80 += vq4;       a82 += vq3 * cr2; a84 += vq2 * cr4;              \
            a86 += vq1 * cr6; a88 += vq0 * cr8;                                \
            a91 += vq4 * cr1; a93 += vq3 * cr3; a95 += vq2 * cr5;              \
            a97 += vq1 * cr7; a99 += vq0 * cr9;                                \
            b11 += vq0 * ci1;                                                  \
            b22 += vq0 * ci2;                                                  \
            b31 += vq1 * ci1; b33 += vq0 * ci3;                                \
            b42 += vq1 * ci2; b44 += vq0 * ci4;                                \
            b51 += vq2 * ci1; b53 += vq1 * ci3; b55 += vq0 * ci5;              \
            b62 += vq2 * ci2; b64 += vq1 * ci4; b66 += vq0 * ci6;              \
            b71 += vq3 * ci1; b73 += vq2 * ci3; b75 += vq1 * ci5;              \
            b77 += vq0 * ci7;                                                  \
            b82 += vq3 * ci2; b84 += vq2 * ci4; b86 += vq1 * ci6;              \
            b88 += vq0 * ci8;                                                  \
            b91 += vq4 * ci1; b93 += vq3 * ci3; b95 += vq2 * ci5;              \
            b97 += vq1 * ci7; b99 += vq0 * ci9;                                \
        }                                                                      \
    }

#define WRED(var, idx)                                                     \
    {                                                                      \
        float r_ = var;                                                    \
        _Pragma("unroll")                                                  \
        for (int off_ = 32; off_; off_ >>= 1) r_ += __shfl_down(r_, off_); \
        if (lane == 0) red[w * 64 + (idx)] = r_;                           \
    }

// ---------------------------------------------------------------------------
// Kernel B (FUSED col FFT + stats), VALU-diet edition. R9 vs R10 accounting:
// identical VALU time (102 vs 104 us), duration differs only via issue
// density — and (256,4) [R9, VGPR 64 + benign overlapped spills] measured
// FASTER (172) than spill-free (256,2) [R10, 200]. So: restore (256,4) and
// attack the invariant ~102us of VALU work itself via the Cartesian Zernike
// rewrite (no sqrt/rsqrt/Chebyshev; see ZPIX) — also shrinks the stats live
// set, which should reduce the spill volume at the 64-VGPR cap.
// Partial target rf2 row (b, k0+2): disjointness proof unchanged from R8.
// ---------------------------------------------------------------------------
__global__ __launch_bounds__(256, 4) void fused_col_stats_kernel(float2* __restrict__ rf2,
                                                                 float* __restrict__ magmax) {
    __shared__ float sb[8][1024];       // 32 KB: per-slot scratch, then phases
    __shared__ float red[256];          // 1 KB reduction buffer
    const int tid = threadIdx.x, w = tid >> 6, lane = tid & 63;
    const int n1 = lane & 31, s = lane >> 5;
    const int slot = 2 * w + s;                     // 0..7 = rows k0-1 .. k0+6
    const int bx = blockIdx.x, b = blockIdx.y;
    const int k0 = bx * 6;
    int kf = k0 - 1 + slot;
    kf = kf < 0 ? 0 : (kf > WR - 1 ? WR - 1 : kf);  // clamped halo (dupes unused)
    const float2* src = rf2 + ((long long)b * WR + kf) * 1024;

    // ---- four-step 1024-pt FFT over this slot's row ----
    float2 d[32];
#pragma unroll
    for (int j = 0; j < 32; ++j) d[j] = src[n1 + 32 * j];
    fft32_dif(d);                                   // d[brev5(k1)] = A[n1][k1]
    float s0, c0;
    __sincosf(-TWO_PI_F * (float)n1 * (1.0f / 1024.0f), &s0, &c0);
    const float2 Tn = make_float2(c0, s0);
    float2 ww = Tn;
#pragma unroll
    for (int k1 = 1; k1 < 32; ++k1) {
        d[brev5(k1)] = cmul(d[brev5(k1)], ww);
        if (k1 < 31) ww = cmul(ww, Tn);
    }
    // Two-pass b32 transpose through the 4 KB slot (XOR swizzle, 2 lanes/bank).
    float* scr = &sb[slot][0];
#pragma unroll
    for (int k1 = 0; k1 < 32; ++k1) scr[(k1 << 5) | (n1 ^ k1)] = d[brev5(k1)].x;
    LGKM_SYNC();
    float tx[32];
#pragma unroll
    for (int j = 0; j < 32; ++j) tx[j] = scr[(n1 << 5) | (j ^ n1)];
    LGKM_SYNC();                        // .x reads done before .y overwrite
#pragma unroll
    for (int k1 = 0; k1 < 32; ++k1) scr[(k1 << 5) | (n1 ^ k1)] = d[brev5(k1)].y;
    LGKM_SYNC();
#pragma unroll
    for (int j = 0; j < 32; ++j) d[j] = make_float2(tx[j], scr[(n1 << 5) | (j ^ n1)]);
    fft32_dif(d);                                   // d[brev5(k2)] = X[n1 + 32*k2]

    // ---- epilogue: phase -> LDS (same slot; DS in-order + data dep), mag ----
    float mmax = 0.0f;
#pragma unroll
    for (int k2 = 0; k2 < 32; ++k2) {
        float2 z = d[brev5(k2)];
        mmax = fmaxf(mmax, __builtin_amdgcn_sqrtf(z.x * z.x + z.y * z.y));
        float ph = fast_atan2f(z.y, z.x);
        scr[32 * k2 + n1] = (ph < 0.0f) ? ph + TWO_PI_F : ph;   // == phase[h]
    }
#pragma unroll
    for (int off = 16; off; off >>= 1) mmax = fmaxf(mmax, __shfl_xor(mmax, off, 64));
    if (n1 == 0) atomicMax((int*)(magmax + b), __float_as_int(mmax));
    __syncthreads();                                // all 8 phase rows visible

    // ---- stats: float4 per thread per row (h4 = tid*4 covers 0..1023) ----
    float a00 = 0.f, a11 = 0.f, a20 = 0.f, a22 = 0.f, a31 = 0.f, a33 = 0.f,
          a40 = 0.f, a42 = 0.f, a44 = 0.f, a51 = 0.f, a53 = 0.f, a55 = 0.f,
          a60 = 0.f, a62 = 0.f, a64 = 0.f, a66 = 0.f, a71 = 0.f, a73 = 0.f,
          a75 = 0.f, a77 = 0.f, a80 = 0.f, a82 = 0.f, a84 = 0.f, a86 = 0.f,
          a88 = 0.f, a91 = 0.f, a93 = 0.f, a95 = 0.f, a97 = 0.f, a99 = 0.f;
    float b11 = 0.f, b22 = 0.f, b31 = 0.f, b33 = 0.f, b42 = 0.f, b44 = 0.f,
          b51 = 0.f, b53 = 0.f, b55 = 0.f, b62 = 0.f, b64 = 0.f, b66 = 0.f,
          b71 = 0.f, b73 = 0.f, b75 = 0.f, b77 = 0.f, b82 = 0.f, b84 = 0.f,
          b86 = 0.f, b88 = 0.f, b91 = 0.f, b93 = 0.f, b95 = 0.f, b97 = 0.f,
          b99 = 0.f;
    float sgx = 0.f, sgx2 = 0.f, sgy = 0.f, sgy2 = 0.f, cnt = 0.f;

    const int h4 = tid * 4;
    const float ystep = 2.0f / 1023.0f;
    const float yv0 = -1.0f + ystep * (float)h4;

    for (int sl = 1; sl <= 6; ++sl) {
        const int k = k0 + sl - 1;
        if (k > WR - 1) break;
        const float xv = -1.0f + (1.0f / 256.0f) * (float)k;
        const float xv2 = xv * xv;
        const float* pc = &sb[sl][0];
        const float* pm = &sb[sl - 1][0];
        const float* pp = &sb[sl + 1][0];
        const float4 vc = *reinterpret_cast<const float4*>(pc + h4);
        float4 gx4;
        if (k == 0) {
            const float4 vp = *reinterpret_cast<const float4*>(pp + h4);
            gx4 = make_float4(vp.x - vc.x, vp.y - vc.y, vp.z - vc.z, vp.w - vc.w);
        } else if (k == WR - 1) {
            const float4 vm = *reinterpret_cast<const float4*>(pm + h4);
            gx4 = make_float4(vc.x - vm.x, vc.y - vm.y, vc.z - vm.z, vc.w - vm.w);
        } else {
            const float4 vm = *reinterpret_cast<const float4*>(pm + h4);
            const float4 vp = *reinterpret_cast<const float4*>(pp + h4);
            gx4 = make_float4(0.5f * (vp.x - vm.x), 0.5f * (vp.y - vm.y),
                              0.5f * (vp.z - vm.z), 0.5f * (vp.w - vm.w));
        }
        const float left  = pc[h4 > 0 ? h4 - 1 : 0];
        const float right = pc[h4 < 1020 ? h4 + 4 : 1023];
        const float gy0 = (h4 == 0)    ? vc.y - vc.x : 0.5f * (vc.y - left);
        const float gy1 = 0.5f * (vc.z - vc.x);
        const float gy2 = 0.5f * (vc.w - vc.y);
        const float gy3 = (h4 == 1020) ? vc.w - vc.z : 0.5f * (right - vc.z);

        sgx  += gx4.x + gx4.y + gx4.z + gx4.w;
        sgx2 += gx4.x * gx4.x + gx4.y * gx4.y + gx4.z * gx4.z + gx4.w * gx4.w;
        sgy  += gy0 + gy1 + gy2 + gy3;
        sgy2 += gy0 * gy0 + gy1 * gy1 + gy2 * gy2 + gy3 * gy3;

        ZPIX(vc.x, yv0);
        ZPIX(vc.y, yv0 + ystep);
        ZPIX(vc.z, yv0 + 2.0f * ystep);
        ZPIX(vc.w, yv0 + 3.0f * ystep);
    }

    WRED(a00, 0);  WRED(a11, 1);  WRED(a20, 2);  WRED(a22, 3);  WRED(a31, 4);
    WRED(a33, 5);  WRED(a40, 6);  WRED(a42, 7);  WRED(a44, 8);  WRED(a51, 9);
    WRED(a53, 10); WRED(a55, 11); WRED(a60, 12); WRED(a62, 13); WRED(a64, 14);
    WRED(a66, 15); WRED(a71, 16); WRED(a73, 17); WRED(a75, 18); WRED(a77, 19);
    WRED(a80, 20); WRED(a82, 21); WRED(a84, 22); WRED(a86, 23); WRED(a88, 24);
    WRED(a91, 25); WRED(a93, 26); WRED(a95, 27); WRED(a97, 28); WRED(a99, 29);
    WRED(b11, 30); WRED(b22, 31); WRED(b31, 32); WRED(b33, 33); WRED(b42, 34);
    WRED(b44, 35); WRED(b51, 36); WRED(b53, 37); WRED(b55, 38); WRED(b62, 39);
    WRED(b64, 40); WRED(b66, 41); WRED(b71, 42); WRED(b73, 43); WRED(b75, 44);
    WRED(b77, 45); WRED(b82, 46); WRED(b84, 47); WRED(b86, 48); WRED(b88, 49);
    WRED(b91, 50); WRED(b93, 51); WRED(b95, 52); WRED(b97, 53); WRED(b99, 54);
    WRED(sgx, 55); WRED(sgx2, 56); WRED(sgy, 57); WRED(sgy2, 58); WRED(cnt, 59);
    __syncthreads();
    if (tid < 60) {
        float sum = red[tid] + red[64 + tid] + red[128 + tid] + red[192 + tid];
        // Partial -> rf2 row (b, k0+2): disjoint from all blocks' read sets.
        float* pdst = (float*)(rf2 + ((long long)b * WR + k0 + 2) * 1024);
        pdst[tid] = sum;
    }
}

// ---------------------------------------------------------------------------
// Kernel D: sum 86 block-partials per batch, map moments -> coeffs, stats.
// ---------------------------------------------------------------------------
__device__ int moment_index(int p, int a, int is_cos) {
    int ai = 0;
    for (int pp = 0; pp < 10; ++pp)
        for (int aa = (pp & 1); aa <= pp; aa += 2) {
            if (is_cos && pp == p && aa == a) return ai;
            ++ai;
        }
    for (int pp = 1; pp < 10; ++pp)
        for (int aa = ((pp & 1) ? 1 : 2); aa <= pp; aa += 2) {
            if (!is_cos && pp == p && aa == a) return ai;
            ++ai;
        }
    return 0;
}

__device__ float factf(int n) {
    float f = 1.0f;
    for (int i = 2; i <= n; ++i) f *= (float)i;
    return f;
}

__global__ void finalize_kernel(const float* __restrict__ rf2f,
                                const float* __restrict__ magmax,
                                float* __restrict__ out) {
    __shared__ float abf[64];
    const int b = blockIdx.x;
    const int j = threadIdx.x;
    if (j < 60) {
        float s = 0.0f;
        for (int i = 0; i < 86; ++i)
            s += rf2f[((long long)b * WR + 6 * i + 2) * 2048 + j];
        abf[j] = s;
    }
    __syncthreads();
    if (j >= 60) return;
    const float NF = (float)NPIX;
    float val;
    if (j < 55) {
        int tt = j, n = 0;
        while (tt >= n + 1) { tt -= (n + 1); ++n; }
        int m = -n + 2 * tt;
        int am = m < 0 ? -m : m;
        float s = 0.0f;
        for (int k = 0; k <= (n - am) / 2; ++k) {
            float c = factf(n - k) /
                      (factf(k) * factf((n + am) / 2 - k) * factf((n - am) / 2 - k));
            if (k & 1) c = -c;
            int p = n - 2 * k;
            s += c * abf[moment_index(p, am, m >= 0 ? 1 : 0)];
        }
        val = s / abf[59];
    } else if (j == 55) {
        val = abf[55] / NF;
    } else if (j == 56) {
        val = abf[57] / NF;
    } else if (j == 57) {
        float sum = abf[55], sq = abf[56];
        val = sqrtf(fmaxf(0.0f, (sq - sum * sum / NF) / (NF - 1.0f)));
    } else if (j == 58) {
        float sum = abf[57], sq = abf[58];
        val = sqrtf(fmaxf(0.0f, (sq - sum * sum / NF) / (NF - 1.0f)));
    } else {
        val = magmax[b];
    }
    out[b * 60 + j] = val;
}

// ---------------------------------------------------------------------------
extern "C" void kernel_launch(void* const* d_in, const int* in_sizes, int n_in,
                              void* d_out, int out_size, void* d_ws, size_t ws_size,
                              hipStream_t stream) {
    (void)in_sizes; (void)n_in; (void)out_size; (void)ws_size;
    const float* x = (const float*)d_in[0];
    float* out = (float*)d_out;

    float* magmax = (float*)d_ws;                  // 32 floats (atomicMax target)
    float2* rf2 = (float2*)((char*)d_ws + 16384);  // [B][WR][H] float2 = 134.5 MB

    hipMemsetAsync(d_ws, 0, 16384, stream);
    row_fft_kernel<<<BATCH * 128, 256, 0, stream>>>(x, rf2);
    // 86 blocks x 6 useful rows cover the 513 k-rows of each batch.
    dim3 gridF(86, BATCH);
    fused_col_stats_kernel<<<gridF, 256, 0, stream>>>(rf2, magmax);
    finalize_kernel<<<BATCH, 64, 0, stream>>>((const float*)rf2, magmax, out);
}

// Round 12
// 416.094 us; speedup vs baseline: 1.1664x; 1.1664x over previous
//
#include <hip/hip_runtime.h>
#include <math.h>

#define BATCH 32
#define HH 1024
#define WW 1024
#define WR 513
#define NPIX (HH * WR)
#define TWO_PI_F 6.28318530717958647692f

// Same-wave LDS fence: wait for this wave's own LDS ops.
#define LGKM_SYNC() __asm__ __volatile__("s_waitcnt lgkmcnt(0)" ::: "memory")

__device__ __forceinline__ float2 cadd(float2 a, float2 b) { return make_float2(a.x + b.x, a.y + b.y); }
__device__ __forceinline__ float2 csub(float2 a, float2 b) { return make_float2(a.x - b.x, a.y - b.y); }
__device__ __forceinline__ float2 cmul(float2 a, float2 b) {
    return make_float2(a.x * b.x - a.y * b.y, a.x * b.y + a.y * b.x);
}

// atan2 via odd minimax poly on [0,1] (max err ~1e-5 rad) + quadrant fixup.
__device__ __forceinline__ float fast_atan2f(float y, float x) {
    float ax = __builtin_fabsf(x), ay = __builtin_fabsf(y);
    float mx = fmaxf(ax, ay), mn = fminf(ax, ay);
    float a = mn * __builtin_amdgcn_rcpf(mx);
    float s = a * a;
    float r = fmaf(fmaf(fmaf(fmaf(0.0208351f, s, -0.085133f), s, 0.180141f),
                        s, -0.3302995f), s, 0.999866f) * a;
    if (ay > ax) r = 1.5707963268f - r;
    if (x < 0.0f) r = 3.1415926536f - r;
    return (y < 0.0f) ? -r : r;
}

// ---------------- 16-point building blocks (row_fft path, unchanged) -------
__device__ __forceinline__ constexpr int ridx(int k) { return ((k & 3) << 2) | (k >> 2); }

__device__ __forceinline__ void fft16_ip(float2* d) {
    const float2 Wt1[4] = {{1.f, 0.f},
                           {0.92387953f, -0.38268343f},
                           {0.70710678f, -0.70710678f},
                           {0.38268343f, -0.92387953f}};
    const float2 Wt2[4] = {{1.f, 0.f},
                           {0.70710678f, -0.70710678f},
                           {0.f, -1.f},
                           {-0.70710678f, -0.70710678f}};
    const float2 Wt3[4] = {{1.f, 0.f},
                           {0.38268343f, -0.92387953f},
                           {-0.70710678f, -0.70710678f},
                           {-0.92387953f, 0.38268343f}};
#pragma unroll
    for (int t = 0; t < 4; ++t) {
        float2 x0 = d[t], x1 = d[t + 4], x2 = d[t + 8], x3 = d[t + 12];
        float2 a0 = cadd(x0, x2), a1 = csub(x0, x2), a2 = cadd(x1, x3), a3 = csub(x1, x3);
        d[t]      = cadd(a0, a2);
        d[t + 4]  = cmul(make_float2(a1.x + a3.y, a1.y - a3.x), Wt1[t]);
        d[t + 8]  = cmul(csub(a0, a2), Wt2[t]);
        d[t + 12] = cmul(make_float2(a1.x - a3.y, a1.y + a3.x), Wt3[t]);
    }
#pragma unroll
    for (int r = 0; r < 4; ++r) {
        float2 x0 = d[4 * r], x1 = d[4 * r + 1], x2 = d[4 * r + 2], x3 = d[4 * r + 3];
        float2 e0 = cadd(x0, x2), e1 = csub(x0, x2), e2 = cadd(x1, x3), e3 = csub(x1, x3);
        d[4 * r]     = cadd(e0, e2);
        d[4 * r + 1] = make_float2(e1.x + e3.y, e1.y - e3.x);
        d[4 * r + 2] = csub(e0, e2);
        d[4 * r + 3] = make_float2(e1.x - e3.y, e1.y + e3.x);
    }
}

__device__ __forceinline__ void twiddle_tree(float2 T, float2* Wt) {
    Wt[1] = T;
    Wt[2] = cmul(T, T);
    Wt[3] = cmul(Wt[2], T);
    Wt[4] = cmul(Wt[2], Wt[2]);
    Wt[5] = cmul(Wt[4], Wt[1]);
    Wt[6] = cmul(Wt[4], Wt[2]);
    Wt[7] = cmul(Wt[4], Wt[3]);
    Wt[8] = cmul(Wt[4], Wt[4]);
    Wt[9]  = cmul(Wt[8], Wt[1]);
    Wt[10] = cmul(Wt[8], Wt[2]);
    Wt[11] = cmul(Wt[8], Wt[3]);
    Wt[12] = cmul(Wt[8], Wt[4]);
    Wt[13] = cmul(Wt[8], Wt[5]);
    Wt[14] = cmul(Wt[8], Wt[6]);
    Wt[15] = cmul(Wt[8], Wt[7]);
}

// Wave-level 1024-pt FFT (row_fft_kernel only).
__device__ __forceinline__ void wave_fft1024(float2* v, float2* sb, int lane) {
    fft16_ip(v);
    float s, c;
    __sincosf(-TWO_PI_F * (float)lane * (1.0f / 1024.0f), &s, &c);
    float2 Wt[16];
    twiddle_tree(make_float2(c, s), Wt);
#pragma unroll
    for (int k2 = 1; k2 < 16; ++k2) v[ridx(k2)] = cmul(v[ridx(k2)], Wt[k2]);
    const int k2p = lane & 15, qp = lane >> 4;
#pragma unroll
    for (int k2 = 0; k2 < 16; ++k2) sb[(k2 << 6) | (lane ^ k2)] = v[ridx(k2)];
    LGKM_SYNC();
#pragma unroll
    for (int m = 0; m < 16; ++m) v[m] = sb[(k2p << 6) | ((4 * m + qp) ^ k2p)];
    LGKM_SYNC();
    fft16_ip(v);
    __sincosf(-TWO_PI_F * (float)qp * (1.0f / 64.0f), &s, &c);
    twiddle_tree(make_float2(c, s), Wt);
#pragma unroll
    for (int km = 1; km < 16; ++km) v[ridx(km)] = cmul(v[ridx(km)], Wt[km]);
    const bool hi2 = (lane & 32) != 0, hi1 = (lane & 16) != 0;
#pragma unroll
    for (int m = 0; m < 16; ++m) {
        float2 a = v[m];
        float2 o = make_float2(__shfl_xor(a.x, 32, 64), __shfl_xor(a.y, 32, 64));
        float2 s1 = hi2 ? csub(o, a) : cadd(a, o);
        if (hi2 && hi1) s1 = make_float2(s1.y, -s1.x);
        float2 o2 = make_float2(__shfl_xor(s1.x, 16, 64), __shfl_xor(s1.y, 16, 64));
        v[m] = hi1 ? csub(o2, s1) : cadd(s1, o2);
    }
}

// ---------------------------------------------------------------------------
// Kernel A: unchanged.
// ---------------------------------------------------------------------------
__global__ __launch_bounds__(256, 4) void row_fft_kernel(const float* __restrict__ x,
                                                         float2* __restrict__ rf2) {
    __shared__ float2 buf[4][1024];
    const int t = threadIdx.x, w = t >> 6, lane = t & 63;
    const int b = blockIdx.x >> 7;
    const int h0 = (blockIdx.x & 127) * 8;
    const float* r0 = x + ((long long)b * HH + h0 + 2 * w) * (long long)WW;
    const float* r1 = r0 + WW;
    float2 v[16];
#pragma unroll
    for (int j = 0; j < 16; ++j) v[j] = make_float2(r0[lane + 64 * j], r1[lane + 64 * j]);
    float2* mybuf = &buf[w][0];
    wave_fft1024(v, mybuf, lane);
    const int kq = 2 * ((lane >> 4) & 1) + ((lane >> 5) & 1);
    const int kbase = (lane & 15) + 256 * kq;
#pragma unroll
    for (int m = 0; m < 16; ++m) mybuf[kbase + 16 * m] = v[ridx(m)];
    __syncthreads();
    for (int idx = t; idx < 513 * 8; idx += 256) {
        int k = idx >> 3, j = idx & 7, p = j >> 1, which = j & 1;
        float2 zk = buf[p][k];
        float2 zn = buf[p][(1024 - k) & 1023];
        float2 val = which ? make_float2(0.5f * (zk.y + zn.y), 0.5f * (zn.x - zk.x))
                           : make_float2(0.5f * (zk.x + zn.x), 0.5f * (zk.y - zn.y));
        rf2[((long long)b * WR + k) * 1024 + h0 + j] = val;
    }
}

// ------------------------- 32-point FFT (four-step) ------------------------
__device__ __forceinline__ constexpr int brev5(int k) {
    return ((k & 1) << 4) | ((k & 2) << 2) | (k & 4) | ((k & 8) >> 2) | ((k & 16) >> 4);
}

__device__ __forceinline__ void fft32_dif(float2* d) {
    const float2 TW[16] = {
        {1.f, 0.f},
        {0.98078528f, -0.19509032f},
        {0.92387953f, -0.38268343f},
        {0.83146961f, -0.55557023f},
        {0.70710678f, -0.70710678f},
        {0.55557023f, -0.83146961f},
        {0.38268343f, -0.92387953f},
        {0.19509032f, -0.98078528f},
        {0.f, -1.f},
        {-0.19509032f, -0.98078528f},
        {-0.38268343f, -0.92387953f},
        {-0.55557023f, -0.83146961f},
        {-0.70710678f, -0.70710678f},
        {-0.83146961f, -0.55557023f},
        {-0.92387953f, -0.38268343f},
        {-0.98078528f, -0.19509032f}};
#pragma unroll
    for (int s = 0; s < 5; ++s) {
        const int h = 16 >> s;
#pragma unroll
        for (int b = 0; b < 32; b += 2 * h) {
#pragma unroll
            for (int j = 0; j < h; ++j) {
                float2 a = d[b + j], c = d[b + j + h];
                d[b + j]     = cadd(a, c);
                d[b + j + h] = cmul(csub(a, c), TW[j << s]);
            }
        }
    }
}

// Cartesian Zernike accumulation for one pixel. Identity:
//   rho^p cos(a*theta) = r2^((p-a)/2) * Re((x+iy)^a)   [(p-a) always even]
// so moment(p,a) = sum v * vq_{(p-a)/2} * {Re,Im}(u^a). Removes sqrtf +
// rsqrtf (quarter-rate transcendentals) and both depth-8 Chebyshev chains;
// complex-power tree has depth 4. Exact algebra, bounded domain (rho<=1).
// NOTE: needs the 128-VGPR budget — at a 64-VGPR cap its wide live set
// spills 192MB (R11). Verified numerically correct (R11 passed, 6.1e-5).
#define ZPIX(VV, YVV)                                                          \
    {                                                                          \
        const float yv_ = (YVV);                                               \
        const float r2_ = xv2 + yv_ * yv_;                                     \
        if (r2_ <= 1.0f) {                                                     \
            cnt += 1.0f;                                                       \
            const float p2_ = r2_ * r2_, p3_ = p2_ * r2_, p4_ = p2_ * p2_;     \
            const float vq0 = (VV);                                            \
            const float vq1 = vq0 * r2_, vq2 = vq0 * p2_,                      \
                        vq3 = vq0 * p3_, vq4 = vq0 * p4_;                      \
            const float cr1 = xv,            ci1 = yv_;                        \
            const float cr2 = xv * xv - yv_ * yv_, ci2 = 2.f * xv * yv_;       \
            const float cr3 = cr2 * cr1 - ci2 * ci1,                           \
                        ci3 = cr2 * ci1 + ci2 * cr1;                           \
            const float cr4 = cr2 * cr2 - ci2 * ci2, ci4 = 2.f * cr2 * ci2;    \
            const float cr5 = cr4 * cr1 - ci4 * ci1,                           \
                        ci5 = cr4 * ci1 + ci4 * cr1;                           \
            const float cr6 = cr4 * cr2 - ci4 * ci2,                           \
                        ci6 = cr4 * ci2 + ci4 * cr2;                           \
            const float cr7 = cr4 * cr3 - ci4 * ci3,                           \
                        ci7 = cr4 * ci3 + ci4 * cr3;                           \
            const float cr8 = cr4 * cr4 - ci4 * ci4, ci8 = 2.f * cr4 * ci4;    \
            const float cr9 = cr8 * cr1 - ci8 * ci1,                           \
                        ci9 = cr8 * ci1 + ci8 * cr1;                           \
            a00 += vq0;                                                        \
            a11 += vq0 * cr1;                                                  \
            a20 += vq1;       a22 += vq0 * cr2;                                \
            a31 += vq1 * cr1; a33 += vq0 * cr3;                                \
            a40 += vq2;       a42 += vq1 * cr2; a44 += vq0 * cr4;              \
            a51 += vq2 * cr1; a53 += vq1 * cr3; a55 += vq0 * cr5;              \
            a60 += vq3;       a62 += vq2 * cr2; a64 += vq1 * cr4;              \
            a66 += vq0 * cr6;                                                  \
            a71 += vq3 * cr1; a73 += vq2 * cr3; a75 += vq1 * cr5;              \
            a77 += vq0 * cr7;                                                  \
            a80 += vq4;       a82 += vq3 * cr2; a84 += vq2 * cr4;              \
            a86 += vq1 * cr6; a88 += vq0 * cr8;                                \
            a91 += vq4 * cr1; a93 += vq3 * cr3; a95 += vq2 * cr5;              \
            a97 += vq1 * cr7; a99 += vq0 * cr9;                                \
            b11 += vq0 * ci1;                                                  \
            b22 += vq0 * ci2;                                                  \
            b31 += vq1 * ci1; b33 += vq0 * ci3;                                \
            b42 += vq1 * ci2; b44 += vq0 * ci4;                                \
            b51 += vq2 * ci1; b53 += vq1 * ci3; b55 += vq0 * ci5;              \
            b62 += vq2 * ci2; b64 += vq1 * ci4; b66 += vq0 * ci6;              \
            b71 += vq3 * ci1; b73 += vq2 * ci3; b75 += vq1 * ci5;              \
            b77 += vq0 * ci7;                                                  \
            b82 += vq3 * ci2; b84 += vq2 * ci4; b86 += vq1 * ci6;              \
            b88 += vq0 * ci8;                                                  \
            b91 += vq4 * ci1; b93 += vq3 * ci3; b95 += vq2 * ci5;              \
            b97 += vq1 * ci7; b99 += vq0 * ci9;                                \
        }                                                                      \
    }

#define WRED(var, idx)                                                     \
    {                                                                      \
        float r_ = var;                                                    \
        _Pragma("unroll")                                                  \
        for (int off_ = 32; off_; off_ >>= 1) r_ += __shfl_down(r_, off_); \
        if (lane == 0) red[w * 64 + (idx)] = r_;                           \
    }

// ---------------------------------------------------------------------------
// Kernel B (FUSED col FFT + stats). 2x2 A/B completed this round:
//   (256,4)+Chebyshev: 172us, 20MB spill (R9)  | (256,4)+Cartesian: 240us, 192MB spill (R11)
//   (256,2)+Chebyshev: 200us, spill-free (R10) | (256,2)+Cartesian: THIS CELL
// Cartesian ZPIX saves ~15-20% VALU ops (no sqrt/rsqrt/Chebyshev chains) but
// its wide tree live set needs the 128-VGPR budget of (256,2) to stay
// spill-free (R10 proved this config holds the kernel at 68 VGPR, 1MB WRITE).
// Partial target rf2 row (b, k0+2): disjointness proof unchanged from R8.
// ---------------------------------------------------------------------------
__global__ __launch_bounds__(256, 2) void fused_col_stats_kernel(float2* __restrict__ rf2,
                                                                 float* __restrict__ magmax) {
    __shared__ float sb[8][1024];       // 32 KB: per-slot scratch, then phases
    __shared__ float red[256];          // 1 KB reduction buffer
    const int tid = threadIdx.x, w = tid >> 6, lane = tid & 63;
    const int n1 = lane & 31, s = lane >> 5;
    const int slot = 2 * w + s;                     // 0..7 = rows k0-1 .. k0+6
    const int bx = blockIdx.x, b = blockIdx.y;
    const int k0 = bx * 6;
    int kf = k0 - 1 + slot;
    kf = kf < 0 ? 0 : (kf > WR - 1 ? WR - 1 : kf);  // clamped halo (dupes unused)
    const float2* src = rf2 + ((long long)b * WR + kf) * 1024;

    // ---- four-step 1024-pt FFT over this slot's row ----
    float2 d[32];
#pragma unroll
    for (int j = 0; j < 32; ++j) d[j] = src[n1 + 32 * j];
    fft32_dif(d);                                   // d[brev5(k1)] = A[n1][k1]
    float s0, c0;
    __sincosf(-TWO_PI_F * (float)n1 * (1.0f / 1024.0f), &s0, &c0);
    const float2 Tn = make_float2(c0, s0);
    float2 ww = Tn;
#pragma unroll
    for (int k1 = 1; k1 < 32; ++k1) {
        d[brev5(k1)] = cmul(d[brev5(k1)], ww);
        if (k1 < 31) ww = cmul(ww, Tn);
    }
    // Two-pass b32 transpose through the 4 KB slot (XOR swizzle, 2 lanes/bank).
    float* scr = &sb[slot][0];
#pragma unroll
    for (int k1 = 0; k1 < 32; ++k1) scr[(k1 << 5) | (n1 ^ k1)] = d[brev5(k1)].x;
    LGKM_SYNC();
    float tx[32];
#pragma unroll
    for (int j = 0; j < 32; ++j) tx[j] = scr[(n1 << 5) | (j ^ n1)];
    LGKM_SYNC();                        // .x reads done before .y overwrite
#pragma unroll
    for (int k1 = 0; k1 < 32; ++k1) scr[(k1 << 5) | (n1 ^ k1)] = d[brev5(k1)].y;
    LGKM_SYNC();
#pragma unroll
    for (int j = 0; j < 32; ++j) d[j] = make_float2(tx[j], scr[(n1 << 5) | (j ^ n1)]);
    fft32_dif(d);                                   // d[brev5(k2)] = X[n1 + 32*k2]

    // ---- epilogue: phase -> LDS (same slot; DS in-order + data dep), mag ----
    float mmax = 0.0f;
#pragma unroll
    for (int k2 = 0; k2 < 32; ++k2) {
        float2 z = d[brev5(k2)];
        mmax = fmaxf(mmax, __builtin_amdgcn_sqrtf(z.x * z.x + z.y * z.y));
        float ph = fast_atan2f(z.y, z.x);
        scr[32 * k2 + n1] = (ph < 0.0f) ? ph + TWO_PI_F : ph;   // == phase[h]
    }
#pragma unroll
    for (int off = 16; off; off >>= 1) mmax = fmaxf(mmax, __shfl_xor(mmax, off, 64));
    if (n1 == 0) atomicMax((int*)(magmax + b), __float_as_int(mmax));
    __syncthreads();                                // all 8 phase rows visible

    // ---- stats: float4 per thread per row (h4 = tid*4 covers 0..1023) ----
    float a00 = 0.f, a11 = 0.f, a20 = 0.f, a22 = 0.f, a31 = 0.f, a33 = 0.f,
          a40 = 0.f, a42 = 0.f, a44 = 0.f, a51 = 0.f, a53 = 0.f, a55 = 0.f,
          a60 = 0.f, a62 = 0.f, a64 = 0.f, a66 = 0.f, a71 = 0.f, a73 = 0.f,
          a75 = 0.f, a77 = 0.f, a80 = 0.f, a82 = 0.f, a84 = 0.f, a86 = 0.f,
          a88 = 0.f, a91 = 0.f, a93 = 0.f, a95 = 0.f, a97 = 0.f, a99 = 0.f;
    float b11 = 0.f, b22 = 0.f, b31 = 0.f, b33 = 0.f, b42 = 0.f, b44 = 0.f,
          b51 = 0.f, b53 = 0.f, b55 = 0.f, b62 = 0.f, b64 = 0.f, b66 = 0.f,
          b71 = 0.f, b73 = 0.f, b75 = 0.f, b77 = 0.f, b82 = 0.f, b84 = 0.f,
          b86 = 0.f, b88 = 0.f, b91 = 0.f, b93 = 0.f, b95 = 0.f, b97 = 0.f,
          b99 = 0.f;
    float sgx = 0.f, sgx2 = 0.f, sgy = 0.f, sgy2 = 0.f, cnt = 0.f;

    const int h4 = tid * 4;
    const float ystep = 2.0f / 1023.0f;
    const float yv0 = -1.0f + ystep * (float)h4;

    for (int sl = 1; sl <= 6; ++sl) {
        const int k = k0 + sl - 1;
        if (k > WR - 1) break;
        const float xv = -1.0f + (1.0f / 256.0f) * (float)k;
        const float xv2 = xv * xv;
        const float* pc = &sb[sl][0];
        const float* pm = &sb[sl - 1][0];
        const float* pp = &sb[sl + 1][0];
        const float4 vc = *reinterpret_cast<const float4*>(pc + h4);
        float4 gx4;
        if (k == 0) {
            const float4 vp = *reinterpret_cast<const float4*>(pp + h4);
            gx4 = make_float4(vp.x - vc.x, vp.y - vc.y, vp.z - vc.z, vp.w - vc.w);
        } else if (k == WR - 1) {
            const float4 vm = *reinterpret_cast<const float4*>(pm + h4);
            gx4 = make_float4(vc.x - vm.x, vc.y - vm.y, vc.z - vm.z, vc.w - vm.w);
        } else {
            const float4 vm = *reinterpret_cast<const float4*>(pm + h4);
            const float4 vp = *reinterpret_cast<const float4*>(pp + h4);
            gx4 = make_float4(0.5f * (vp.x - vm.x), 0.5f * (vp.y - vm.y),
                              0.5f * (vp.z - vm.z), 0.5f * (vp.w - vm.w));
        }
        const float left  = pc[h4 > 0 ? h4 - 1 : 0];
        const float right = pc[h4 < 1020 ? h4 + 4 : 1023];
        const float gy0 = (h4 == 0)    ? vc.y - vc.x : 0.5f * (vc.y - left);
        const float gy1 = 0.5f * (vc.z - vc.x);
        const float gy2 = 0.5f * (vc.w - vc.y);
        const float gy3 = (h4 == 1020) ? vc.w - vc.z : 0.5f * (right - vc.z);

        sgx  += gx4.x + gx4.y + gx4.z + gx4.w;
        sgx2 += gx4.x * gx4.x + gx4.y * gx4.y + gx4.z * gx4.z + gx4.w * gx4.w;
        sgy  += gy0 + gy1 + gy2 + gy3;
        sgy2 += gy0 * gy0 + gy1 * gy1 + gy2 * gy2 + gy3 * gy3;

        ZPIX(vc.x, yv0);
        ZPIX(vc.y, yv0 + ystep);
        ZPIX(vc.z, yv0 + 2.0f * ystep);
        ZPIX(vc.w, yv0 + 3.0f * ystep);
    }

    WRED(a00, 0);  WRED(a11, 1);  WRED(a20, 2);  WRED(a22, 3);  WRED(a31, 4);
    WRED(a33, 5);  WRED(a40, 6);  WRED(a42, 7);  WRED(a44, 8);  WRED(a51, 9);
    WRED(a53, 10); WRED(a55, 11); WRED(a60, 12); WRED(a62, 13); WRED(a64, 14);
    WRED(a66, 15); WRED(a71, 16); WRED(a73, 17); WRED(a75, 18); WRED(a77, 19);
    WRED(a80, 20); WRED(a82, 21); WRED(a84, 22); WRED(a86, 23); WRED(a88, 24);
    WRED(a91, 25); WRED(a93, 26); WRED(a95, 27); WRED(a97, 28); WRED(a99, 29);
    WRED(b11, 30); WRED(b22, 31); WRED(b31, 32); WRED(b33, 33); WRED(b42, 34);
    WRED(b44, 35); WRED(b51, 36); WRED(b53, 37); WRED(b55, 38); WRED(b62, 39);
    WRED(b64, 40); WRED(b66, 41); WRED(b71, 42); WRED(b73, 43); WRED(b75, 44);
    WRED(b77, 45); WRED(b82, 46); WRED(b84, 47); WRED(b86, 48); WRED(b88, 49);
    WRED(b91, 50); WRED(b93, 51); WRED(b95, 52); WRED(b97, 53); WRED(b99, 54);
    WRED(sgx, 55); WRED(sgx2, 56); WRED(sgy, 57); WRED(sgy2, 58); WRED(cnt, 59);
    __syncthreads();
    if (tid < 60) {
        float sum = red[tid] + red[64 + tid] + red[128 + tid] + red[192 + tid];
        // Partial -> rf2 row (b, k0+2): disjoint from all blocks' read sets.
        float* pdst = (float*)(rf2 + ((long long)b * WR + k0 + 2) * 1024);
        pdst[tid] = sum;
    }
}

// ---------------------------------------------------------------------------
// Kernel D: sum 86 block-partials per batch, map moments -> coeffs, stats.
// ---------------------------------------------------------------------------
__device__ int moment_index(int p, int a, int is_cos) {
    int ai = 0;
    for (int pp = 0; pp < 10; ++pp)
        for (int aa = (pp & 1); aa <= pp; aa += 2) {
            if (is_cos && pp == p && aa == a) return ai;
            ++ai;
        }
    for (int pp = 1; pp < 10; ++pp)
        for (int aa = ((pp & 1) ? 1 : 2); aa <= pp; aa += 2) {
            if (!is_cos && pp == p && aa == a) return ai;
            ++ai;
        }
    return 0;
}

__device__ float factf(int n) {
    float f = 1.0f;
    for (int i = 2; i <= n; ++i) f *= (float)i;
    return f;
}

__global__ void finalize_kernel(const float* __restrict__ rf2f,
                                const float* __restrict__ magmax,
                                float* __restrict__ out) {
    __shared__ float abf[64];
    const int b = blockIdx.x;
    const int j = threadIdx.x;
    if (j < 60) {
        float s = 0.0f;
        for (int i = 0; i < 86; ++i)
            s += rf2f[((long long)b * WR + 6 * i + 2) * 2048 + j];
        abf[j] = s;
    }
    __syncthreads();
    if (j >= 60) return;
    const float NF = (float)NPIX;
    float val;
    if (j < 55) {
        int tt = j, n = 0;
        while (tt >= n + 1) { tt -= (n + 1); ++n; }
        int m = -n + 2 * tt;
        int am = m < 0 ? -m : m;
        float s = 0.0f;
        for (int k = 0; k <= (n - am) / 2; ++k) {
            float c = factf(n - k) /
                      (factf(k) * factf((n + am) / 2 - k) * factf((n - am) / 2 - k));
            if (k & 1) c = -c;
            int p = n - 2 * k;
            s += c * abf[moment_index(p, am, m >= 0 ? 1 : 0)];
        }
        val = s / abf[59];
    } else if (j == 55) {
        val = abf[55] / NF;
    } else if (j == 56) {
        val = abf[57] / NF;
    } else if (j == 57) {
        float sum = abf[55], sq = abf[56];
        val = sqrtf(fmaxf(0.0f, (sq - sum * sum / NF) / (NF - 1.0f)));
    } else if (j == 58) {
        float sum = abf[57], sq = abf[58];
        val = sqrtf(fmaxf(0.0f, (sq - sum * sum / NF) / (NF - 1.0f)));
    } else {
        val = magmax[b];
    }
    out[b * 60 + j] = val;
}

// ---------------------------------------------------------------------------
extern "C" void kernel_launch(void* const* d_in, const int* in_sizes, int n_in,
                              void* d_out, int out_size, void* d_ws, size_t ws_size,
                              hipStream_t stream) {
    (void)in_sizes; (void)n_in; (void)out_size; (void)ws_size;
    const float* x = (const float*)d_in[0];
    float* out = (float*)d_out;

    float* magmax = (float*)d_ws;                  // 32 floats (atomicMax target)
    float2* rf2 = (float2*)((char*)d_ws + 16384);  // [B][WR][H] float2 = 134.5 MB

    hipMemsetAsync(d_ws, 0, 16384, stream);
    row_fft_kernel<<<BATCH * 128, 256, 0, stream>>>(x, rf2);
    // 86 blocks x 6 useful rows cover the 513 k-rows of each batch.
    dim3 gridF(86, BATCH);
    fused_col_stats_kernel<<<gridF, 256, 0, stream>>>(rf2, magmax);
    finalize_kernel<<<BATCH, 64, 0, stream>>>((const float*)rf2, magmax, out);
}